// Round 2
// baseline (638.322 us; speedup 1.0000x reference)
//
#include <hip/hip_runtime.h>
#include <math.h>

#define BS   8
#define NPTS 2048
#define CCH  12      // channels per flow
#define NF   2       // flow dim
#define DIM  24      // NF*CCH, feats order: d = f*12 + c
#define KTOP 16
#define TM   128     // candidate tile rows staged in LDS

#define TGT_BASE (BS * NPTS * KTOP * CCH)   // 3145728

// Emulate np.linalg.norm(v) + 1e-8 in float32 exactly:
// s[d] = fl32(v[d]^2); numpy pairwise sum for n=24:
//   r[j] = (s[j] + s[j+8]) + s[j+16];  res = ((r0+r1)+(r2+r3)) + ((r4+r5)+(r6+r7))
// then sqrtf (correctly rounded) + 1e-8f.
__device__ __forceinline__ float np_norm_den(const float* __restrict__ v)
{
#pragma clang fp contract(off)
    float s[DIM];
    #pragma unroll
    for (int d = 0; d < DIM; ++d) s[d] = v[d] * v[d];
    float r[8];
    #pragma unroll
    for (int j = 0; j < 8; ++j) r[j] = (s[j] + s[j + 8]) + s[j + 16];
    float res = ((r[0] + r[1]) + (r[2] + r[3])) + ((r[4] + r[5]) + (r[6] + r[7]));
    return sqrtf(res) + 1e-8f;
}

// ---------------------------------------------------------------------------
// One block = (batch b, chunk of 64 rows). 256 threads = 4 waves.
// lane = row within chunk; wave q scans candidate slice [q*32, q*32+32) of
// each 128-row LDS tile. fp32 throughout, emulating the numpy fp32 reference.
// ---------------------------------------------------------------------------
__global__ __launch_bounds__(256) void spatial_topk_kernel(
    const float* __restrict__ x_c,    // [8][12][2][2048]
    const int*   __restrict__ flow_p,
    float*       __restrict__ out)
{
    __shared__ float sf[TM * DIM];        // 12 KiB: tile of normalized feats
    __shared__ float cand_v[64][64];      // [cand j][row L]
    __shared__ int   cand_i[64][64];
    __shared__ int   sel[64][KTOP];

    const int tid   = threadIdx.x;
    const int lane  = tid & 63;
    const int q     = tid >> 6;
    const int b     = blockIdx.x >> 5;
    const int chunk = blockIdx.x & 31;
    const int n     = chunk * 64 + lane;

    const float* xb = x_c + (size_t)b * CCH * NF * NPTS;

    // Own row's normalized feature vector (bit-identical arithmetic to the
    // tile normalization below, so the self-similarity is consistent).
    float rfn[DIM];
    {
#pragma clang fp contract(off)
        float v[DIM];
        #pragma unroll
        for (int c = 0; c < CCH; ++c)
            #pragma unroll
            for (int f = 0; f < NF; ++f)
                v[f * CCH + c] = xb[(c * NF + f) * NPTS + n];
        const float den = np_norm_den(v);
        #pragma unroll
        for (int d = 0; d < DIM; ++d) rfn[d] = v[d] / den;
    }

    // Running top-16 (unsorted, replace-min). Sentinel -2 < any cosine.
    float tv[KTOP];
    int   ti_[KTOP];
    #pragma unroll
    for (int k = 0; k < KTOP; ++k) { tv[k] = -2.0f; ti_[k] = 0x7fffffff; }
    float cur_min = -2.0f;
    int   min_pos = 0;

    for (int mt = 0; mt < NPTS; mt += TM) {
        __syncthreads();
        // stage raw x_c slices: sf[ml][d] with d = f*12+c, p = c*2+f memory order
        for (int i = tid; i < TM * DIM; i += 256) {
            const int p  = i / TM;          // (c,f) pair in x_c memory order
            const int ml = i % TM;
            const int c  = p >> 1;
            const int f  = p & 1;
            sf[ml * DIM + (f * CCH + c)] = xb[p * NPTS + mt + ml];
        }
        __syncthreads();
        // normalize tile rows in place (fp32, numpy-exact)
        if (tid < TM) {
#pragma clang fp contract(off)
            float v[DIM];
            #pragma unroll
            for (int d = 0; d < DIM; ++d) v[d] = sf[tid * DIM + d];
            const float den = np_norm_den(v);
            #pragma unroll
            for (int d = 0; d < DIM; ++d) sf[tid * DIM + d] = v[d] / den;
        }
        __syncthreads();

        const int base = q * (TM / 4);
        for (int j = 0; j < TM / 4; ++j) {
            const int ml = base + j;
            const float* fm = &sf[ml * DIM];   // broadcast: same addr all lanes
            // sequential fp32 FMA chain over d=0..23 (BLAS/Eigen k-loop model)
            float acc = 0.0f;
            #pragma unroll
            for (int d = 0; d < DIM; ++d) acc = __builtin_fmaf(fm[d], rfn[d], acc);
            const int mg = mt + ml;
            if (acc > cur_min) {   // equal -> keep resident (lower index): stable
                #pragma unroll
                for (int k = 0; k < KTOP; ++k)
                    if (k == min_pos) { tv[k] = acc; ti_[k] = mg; }
                // recompute min: smallest value; tie -> LARGEST index (so the
                // lower-index duplicate survives, matching stable top_k)
                cur_min = tv[0]; min_pos = 0; int cmi = ti_[0];
                #pragma unroll
                for (int k = 1; k < KTOP; ++k) {
                    const bool sm = (tv[k] < cur_min) ||
                                    (tv[k] == cur_min && ti_[k] > cmi);
                    if (sm) { cur_min = tv[k]; cmi = ti_[k]; min_pos = k; }
                }
            }
        }
    }

    __syncthreads();
    #pragma unroll
    for (int k = 0; k < KTOP; ++k) {
        cand_v[q * KTOP + k][lane] = tv[k];
        cand_i[q * KTOP + k][lane] = ti_[k];
    }
    __syncthreads();

    // per-row merge of 4x16 candidates -> descending top-16 (ties: lower index)
    if (tid < 64) {
        for (int k = 0; k < KTOP; ++k) {
            float best = -3.0f; int bj = 0; int bix = 0x7fffffff;
            for (int j = 0; j < 64; ++j) {
                const float v  = cand_v[j][tid];
                const int   ix = cand_i[j][tid];
                if (v > best || (v == best && ix < bix)) { best = v; bj = j; bix = ix; }
            }
            sel[tid][k] = bix;
            cand_v[bj][tid] = -4.0f;   // mark used (below any real value / sentinel)
        }
    }
    __syncthreads();

    const int flow = flow_p[0];
    const float* xf = xb + (size_t)flow * NPTS;   // xf[c*2*2048 + m] = x_c[b,c,flow,m]

    // sx_c[b, n, k, c] = x_c[b, c, flow, sel[n][k]]
    for (int e = tid; e < 64 * KTOP * CCH; e += 256) {
        const int L = e / (KTOP * CCH);
        const int r = e % (KTOP * CCH);
        const int k = r / CCH;
        const int c = r % CCH;
        const int idx = sel[L][k];
        out[(((size_t)b * NPTS + (chunk * 64 + L)) * KTOP + k) * CCH + c] =
            xf[(size_t)c * NF * NPTS + idx];
    }

    // tgt_out[b, c, n] = x_c[b, c, flow, n]
    for (int e = tid; e < CCH * 64; e += 256) {
        const int c = e >> 6;
        const int L = e & 63;
        out[TGT_BASE + ((size_t)b * CCH + c) * NPTS + chunk * 64 + L] =
            xf[(size_t)c * NF * NPTS + chunk * 64 + L];
    }
}

// ---------------------------------------------------------------------------
extern "C" void kernel_launch(void* const* d_in, const int* in_sizes, int n_in,
                              void* d_out, int out_size, void* d_ws, size_t ws_size,
                              hipStream_t stream)
{
    const float* x_c    = (const float*)d_in[0];
    const int*   flow_p = (const int*)d_in[1];
    float*       out    = (float*)d_out;

    spatial_topk_kernel<<<BS * (NPTS / 64), 256, 0, stream>>>(x_c, flow_p, out);
}

// Round 3
// 191.469 us; speedup vs baseline: 3.3338x; 3.3338x over previous
//
#include <hip/hip_runtime.h>
#include <math.h>

#define BS   8
#define NPTS 2048
#define CCH  12      // channels per flow
#define NF   2       // flow dim
#define DIM  24      // NF*CCH, feats order: d = f*12 + c
#define SFP  25      // padded LDS row stride (breaks 16-way bank conflict)
#define KTOP 16
#define TM   128     // candidate tile rows staged in LDS

#define NROWS    (BS * NPTS)
#define TGT_BASE (BS * NPTS * KTOP * CCH)   // 3145728

typedef unsigned long long u64;
typedef unsigned int       u32;

// Emulate np.linalg.norm(v) + 1e-8 in float32 exactly (numpy pairwise sum, n=24):
//   r[j] = (s[j] + s[j+8]) + s[j+16];  res = ((r0+r1)+(r2+r3)) + ((r4+r5)+(r6+r7))
__device__ __forceinline__ float np_norm_den(const float* __restrict__ v)
{
#pragma clang fp contract(off)
    float s[DIM];
    #pragma unroll
    for (int d = 0; d < DIM; ++d) s[d] = v[d] * v[d];
    float r[8];
    #pragma unroll
    for (int j = 0; j < 8; ++j) r[j] = (s[j] + s[j + 8]) + s[j + 16];
    float res = ((r[0] + r[1]) + (r[2] + r[3])) + ((r[4] + r[5]) + (r[6] + r[7]));
    return sqrtf(res) + 1e-8f;
}

// Monotone float -> u32 (preserves total order for finite floats)
__device__ __forceinline__ u32 ordf(float f)
{
    u32 u = __float_as_uint(f);
    return ((int)u >= 0) ? (u | 0x80000000u) : ~u;
}

// ---------------------------------------------------------------------------
// Kernel 1: per-row partial top-16 over a candidate slice.
// Block = (batch b, 64-row chunk, candidate split s). 256 thr = 4 waves.
// lane = row; wave q scans rows [q*32, q*32+32) of each 128-cand LDS tile.
// Each block merges its 4 waves' sorted lists -> one sorted 16-list per row
// into ws (u64 keys: ordered-float<<32 | (2047-idx), bigger = better).
// ---------------------------------------------------------------------------
__global__ __launch_bounds__(256) void topk_part_kernel(
    const float* __restrict__ x_c,    // [8][12][2][2048]
    u64*         __restrict__ part,   // [NROWS][SPLIT][KTOP]
    int SPLIT)
{
    __shared__ union {
        float sf[TM * SFP];           // 12.5 KiB: normalized candidate tile
        u64   keys[4][KTOP][64];      // 32 KiB: per-wave sorted lists
    } sh;

    const int tid  = threadIdx.x;
    const int lane = tid & 63;
    const int q    = tid >> 6;
    int bi = blockIdx.x;
    const int s     = bi % SPLIT; bi /= SPLIT;
    const int chunk = bi & 31;
    const int b     = bi >> 5;
    const int n     = chunk * 64 + lane;

    const float* xb = x_c + (size_t)b * CCH * NF * NPTS;

    // Own row's normalized vector — bit-identical arithmetic to tile path.
    float rfn[DIM];
    {
#pragma clang fp contract(off)
        float v[DIM];
        #pragma unroll
        for (int c = 0; c < CCH; ++c)
            #pragma unroll
            for (int f = 0; f < NF; ++f)
                v[f * CCH + c] = xb[(c * NF + f) * NPTS + n];
        const float den = np_norm_den(v);
        #pragma unroll
        for (int d = 0; d < DIM; ++d) rfn[d] = v[d] / den;
    }

    // Sorted-descending top-16 as packed u64 keys. Sentinel 0 < any real key.
    u64 key[KTOP];
    #pragma unroll
    for (int k = 0; k < KTOP; ++k) key[k] = 0ull;

    const int c0  = s * (NPTS / SPLIT);
    const int cpb = NPTS / SPLIT;

    for (int ct = 0; ct < cpb; ct += TM) {
        __syncthreads();
        // stage raw x_c tile: sf[ml][d], d = f*12+c, p = c*2+f memory order
        for (int i = tid; i < TM * DIM; i += 256) {
            const int p  = i / TM;
            const int ml = i % TM;
            const int c  = p >> 1;
            const int f  = p & 1;
            sh.sf[ml * SFP + (f * CCH + c)] = xb[p * NPTS + c0 + ct + ml];
        }
        __syncthreads();
        // normalize tile rows in place (fp32, numpy-exact)
        if (tid < TM) {
#pragma clang fp contract(off)
            float v[DIM];
            #pragma unroll
            for (int d = 0; d < DIM; ++d) v[d] = sh.sf[tid * SFP + d];
            const float den = np_norm_den(v);
            #pragma unroll
            for (int d = 0; d < DIM; ++d) sh.sf[tid * SFP + d] = v[d] / den;
        }
        __syncthreads();

        const int base = q * (TM / 4);
        for (int j = 0; j < TM / 4; ++j) {
            const int ml = base + j;
            const float* fm = &sh.sf[ml * SFP];   // broadcast: same addr all lanes
            // EXACT sequential fp32 FMA chain (matches the passing R2 kernel)
            float acc = 0.0f;
            #pragma unroll
            for (int d = 0; d < DIM; ++d) acc = __builtin_fmaf(fm[d], rfn[d], acc);
            const int mg = c0 + ct + ml;
            const u64 nk = ((u64)ordf(acc) << 32) | (u32)(2047 - mg);
            if (nk > key[KTOP - 1]) {
                // parallel sorted insert: ge[] is a prefix of 1s
                bool ge[KTOP];
                #pragma unroll
                for (int k = 0; k < KTOP; ++k) ge[k] = (key[k] >= nk);
                #pragma unroll
                for (int k = KTOP - 1; k >= 1; --k)
                    key[k] = ge[k] ? key[k] : (ge[k - 1] ? nk : key[k - 1]);
                key[0] = ge[0] ? key[0] : nk;
            }
        }
    }

    __syncthreads();   // all waves done with sf before aliasing as keys
    #pragma unroll
    for (int k = 0; k < KTOP; ++k) sh.keys[q][k][lane] = key[k];
    __syncthreads();

    // per-row 4-way merge of sorted lists -> sorted 16-list, write to ws
    if (tid < 64) {
        int h0 = 0, h1 = 0, h2 = 0, h3 = 0;
        const int row_g = b * NPTS + chunk * 64 + tid;
        u64* dst = part + ((size_t)row_g * SPLIT + s) * KTOP;
        for (int k = 0; k < KTOP; ++k) {
            u64 best = 0; int bq = 0;
            u64 v0 = (h0 < KTOP) ? sh.keys[0][h0][tid] : 0ull;
            u64 v1 = (h1 < KTOP) ? sh.keys[1][h1][tid] : 0ull;
            u64 v2 = (h2 < KTOP) ? sh.keys[2][h2][tid] : 0ull;
            u64 v3 = (h3 < KTOP) ? sh.keys[3][h3][tid] : 0ull;
            if (v0 > best) { best = v0; bq = 0; }
            if (v1 > best) { best = v1; bq = 1; }
            if (v2 > best) { best = v2; bq = 2; }
            if (v3 > best) { best = v3; bq = 3; }
            h0 += (bq == 0); h1 += (bq == 1); h2 += (bq == 2); h3 += (bq == 3);
            dst[k] = best;
        }
    }
}

// ---------------------------------------------------------------------------
// Kernel 2: merge SPLIT sorted 16-lists per row, gather sx_c, write tgt_out.
// Block = 64 rows, 256 threads. Grid = NROWS/64 = 256.
// ---------------------------------------------------------------------------
__global__ __launch_bounds__(256) void merge_gather_kernel(
    const float* __restrict__ x_c,
    const u64*   __restrict__ part,
    const int*   __restrict__ flow_p,
    float*       __restrict__ out,
    int SPLIT)
{
    __shared__ u64 kk[64 * 4 * KTOP];   // up to 32 KiB
    __shared__ int sel[64][KTOP];

    const int tid  = threadIdx.x;
    const int rb   = blockIdx.x * 64;        // first global row of this block
    const int b    = rb / NPTS;
    const int nper = SPLIT * KTOP;

    for (int i = tid; i < 64 * nper; i += 256)
        kk[i] = part[(size_t)rb * nper + i];
    __syncthreads();

    if (tid < 64) {
        const u64* rk = &kk[tid * nper];
        int h0 = 0, h1 = 0, h2 = 0, h3 = 0;
        for (int k = 0; k < KTOP; ++k) {
            u64 best = 0; int bq = 0;
            u64 v0 = rk[h0];
            if (v0 > best) { best = v0; bq = 0; }
            if (SPLIT > 1) {
                u64 v1 = rk[KTOP + h1];
                if (v1 > best) { best = v1; bq = 1; }
            }
            if (SPLIT > 2) {
                u64 v2 = rk[2 * KTOP + h2];
                if (v2 > best) { best = v2; bq = 2; }
                u64 v3 = rk[3 * KTOP + h3];
                if (v3 > best) { best = v3; bq = 3; }
            }
            h0 += (bq == 0); h1 += (bq == 1); h2 += (bq == 2); h3 += (bq == 3);
            sel[tid][k] = 2047 - (int)(best & 0xFFFFFFFFull);
        }
    }
    __syncthreads();

    const int flow = flow_p[0];
    const float* xb = x_c + (size_t)b * CCH * NF * NPTS;
    const float* xf = xb + (size_t)flow * NPTS;   // xf[c*2*2048 + m]

    // sx_c[b, n, k, c] = x_c[b, c, flow, sel[n][k]]
    for (int e = tid; e < 64 * KTOP * CCH; e += 256) {
        const int L = e / (KTOP * CCH);
        const int r = e % (KTOP * CCH);
        const int k = r / CCH;
        const int c = r % CCH;
        out[((size_t)(rb + L) * KTOP + k) * CCH + c] =
            xf[(size_t)c * NF * NPTS + sel[L][k]];
    }

    // tgt_out[b, c, n] = x_c[b, c, flow, n]
    for (int e = tid; e < CCH * 64; e += 256) {
        const int c = e >> 6;
        const int L = e & 63;
        const int n = (rb % NPTS) + L;
        out[TGT_BASE + ((size_t)b * CCH + c) * NPTS + n] =
            xf[(size_t)c * NF * NPTS + n];
    }
}

// ---------------------------------------------------------------------------
extern "C" void kernel_launch(void* const* d_in, const int* in_sizes, int n_in,
                              void* d_out, int out_size, void* d_ws, size_t ws_size,
                              hipStream_t stream)
{
    const float* x_c    = (const float*)d_in[0];
    const int*   flow_p = (const int*)d_in[1];
    float*       out    = (float*)d_out;
    u64*         part   = (u64*)d_ws;

    const size_t need4 = (size_t)NROWS * 4 * KTOP * sizeof(u64);   // 8 MiB
    const int SPLIT = (ws_size >= need4) ? 4 : ((ws_size >= need4 / 2) ? 2 : 1);

    topk_part_kernel<<<BS * 32 * SPLIT, 256, 0, stream>>>(x_c, part, SPLIT);
    merge_gather_kernel<<<NROWS / 64, 256, 0, stream>>>(x_c, part, flow_p, out, SPLIT);
}

// Round 4
// 189.817 us; speedup vs baseline: 3.3628x; 1.0087x over previous
//
#include <hip/hip_runtime.h>
#include <math.h>

#define BS   8
#define NPTS 2048
#define CCH  12      // channels per flow
#define NF   2       // flow dim
#define DIM  24      // NF*CCH, feats order: d = f*12 + c
#define SFP  25      // padded LDS row stride (breaks 16-way bank conflict)
#define KTOP 16
#define TM   128     // candidate tile rows staged in LDS

#define NROWS    (BS * NPTS)
#define TGT_BASE (BS * NPTS * KTOP * CCH)   // 3145728

typedef unsigned long long u64;
typedef unsigned int       u32;
typedef float f32x2 __attribute__((ext_vector_type(2)));

#if __has_builtin(__builtin_elementwise_fma)
#define FMA2(a, b, c) __builtin_elementwise_fma((a), (b), (c))
#else
static __device__ __forceinline__ f32x2 FMA2(f32x2 a, f32x2 b, f32x2 c)
{
    f32x2 r;
    r.x = __builtin_fmaf(a.x, b.x, c.x);
    r.y = __builtin_fmaf(a.y, b.y, c.y);
    return r;
}
#endif

// Emulate np.linalg.norm(v) + 1e-8 in float32 exactly (numpy pairwise sum, n=24):
//   r[j] = (s[j] + s[j+8]) + s[j+16];  res = ((r0+r1)+(r2+r3)) + ((r4+r5)+(r6+r7))
__device__ __forceinline__ float np_norm_den(const float* __restrict__ v)
{
#pragma clang fp contract(off)
    float s[DIM];
    #pragma unroll
    for (int d = 0; d < DIM; ++d) s[d] = v[d] * v[d];
    float r[8];
    #pragma unroll
    for (int j = 0; j < 8; ++j) r[j] = (s[j] + s[j + 8]) + s[j + 16];
    float res = ((r[0] + r[1]) + (r[2] + r[3])) + ((r[4] + r[5]) + (r[6] + r[7]));
    return sqrtf(res) + 1e-8f;
}

// Monotone float -> u32 (preserves total order for finite floats)
__device__ __forceinline__ u32 ordf(float f)
{
    u32 u = __float_as_uint(f);
    return ((int)u >= 0) ? (u | 0x80000000u) : ~u;
}

// ---------------------------------------------------------------------------
// Kernel 1: per-row partial top-16 over a candidate slice.
// Block = (batch b, 64-row chunk, split s). 256 thr = 4 waves; lane = row.
// Wave q scans rows [q*32, q*32+32) of each 128-cand LDS tile, in batches of
// 16 processed BRANCHLESSLY: bitonic-sort batch asc, elementwise-max merge
// with sorted-desc top-16 list, bitonic cleanup. Keys: ordf(val)<<32 |
// (2047-idx)  (bigger = better, ties -> lower index).
// ---------------------------------------------------------------------------
__global__ __launch_bounds__(256, 4) void topk_part_kernel(
    const float* __restrict__ x_c,    // [8][12][2][2048]
    u64*         __restrict__ part,   // [NROWS][SPLIT][KTOP]
    int SPLIT)
{
    __shared__ union {
        float sf[TM * SFP];           // 12.5 KiB: normalized candidate tile
        u64   keys[4][KTOP][64];      // 32 KiB: per-wave sorted lists
    } sh;

    const int tid  = threadIdx.x;
    const int lane = tid & 63;
    const int q    = tid >> 6;
    int bi = blockIdx.x;
    const int s     = bi % SPLIT; bi /= SPLIT;
    const int chunk = bi & 31;
    const int b     = bi >> 5;
    const int n     = chunk * 64 + lane;

    const float* xb = x_c + (size_t)b * CCH * NF * NPTS;

    // Own row's normalized vector — bit-identical arithmetic to tile path.
    float rfn[DIM];
    {
#pragma clang fp contract(off)
        float v[DIM];
        #pragma unroll
        for (int c = 0; c < CCH; ++c)
            #pragma unroll
            for (int f = 0; f < NF; ++f)
                v[f * CCH + c] = xb[(c * NF + f) * NPTS + n];
        const float den = np_norm_den(v);
        #pragma unroll
        for (int d = 0; d < DIM; ++d) rfn[d] = v[d] / den;
    }

    // Sorted-descending top-16 list of packed keys. Sentinel 0 < any real key.
    u64 list[KTOP];
    #pragma unroll
    for (int k = 0; k < KTOP; ++k) list[k] = 0ull;

    const int c0  = s * (NPTS / SPLIT);
    const int cpb = NPTS / SPLIT;

    for (int ct = 0; ct < cpb; ct += TM) {
        __syncthreads();
        // stage raw x_c tile: sf[ml][d], d = f*12+c, p = c*2+f memory order
        for (int i = tid; i < TM * DIM; i += 256) {
            const int p  = i / TM;
            const int ml = i % TM;
            const int c  = p >> 1;
            const int f  = p & 1;
            sh.sf[ml * SFP + (f * CCH + c)] = xb[p * NPTS + c0 + ct + ml];
        }
        __syncthreads();
        // normalize tile rows in place (fp32, numpy-exact)
        if (tid < TM) {
#pragma clang fp contract(off)
            float v[DIM];
            #pragma unroll
            for (int d = 0; d < DIM; ++d) v[d] = sh.sf[tid * SFP + d];
            const float den = np_norm_den(v);
            #pragma unroll
            for (int d = 0; d < DIM; ++d) sh.sf[tid * SFP + d] = v[d] / den;
        }
        __syncthreads();

        // two 16-candidate batches per tile for this wave
        #pragma unroll
        for (int bb = 0; bb < 32; bb += 16) {
            u64 bkey[KTOP];
            // --- dots, packed two candidates per v_pk_fma_f32 ---
            #pragma unroll
            for (int jp = 0; jp < 16; jp += 2) {
                const int ml = q * 32 + bb + jp;
                const float* fA = &sh.sf[ml * SFP];   // broadcast across lanes
                f32x2 acc2 = {0.0f, 0.0f};
                #pragma unroll
                for (int d = 0; d < DIM; ++d) {
                    f32x2 ab = { fA[d], fA[SFP + d] };   // ds_read2_b32
                    f32x2 rr = { rfn[d], rfn[d] };
                    acc2 = FMA2(ab, rr, acc2);           // exact per-cand chain
                }
                const int mg = c0 + ct + ml;
                bkey[jp]     = ((u64)ordf(acc2.x) << 32) | (u32)(2047 - mg);
                bkey[jp + 1] = ((u64)ordf(acc2.y) << 32) | (u32)(2046 - mg);
            }
            // --- bitonic sort batch ASCENDING (branchless, fully unrolled) ---
            #pragma unroll
            for (int k = 2; k <= 16; k <<= 1)
                #pragma unroll
                for (int j = k >> 1; j > 0; j >>= 1)
                    #pragma unroll
                    for (int i = 0; i < 16; ++i) {
                        const int l = i | j;
                        if (l > i) {
                            const bool up = ((i & k) == 0);
                            const u64 a = bkey[i], bv = bkey[l];
                            const bool sw = up ? (a > bv) : (a < bv);
                            bkey[i] = sw ? bv : a;
                            bkey[l] = sw ? a : bv;
                        }
                    }
            // --- merge: list desc + batch asc -> elementwise max is bitonic ---
            #pragma unroll
            for (int i = 0; i < 16; ++i) {
                const u64 a = list[i], bv = bkey[i];
                list[i] = (a > bv) ? a : bv;
            }
            // --- bitonic cleanup -> sorted descending ---
            #pragma unroll
            for (int j = 8; j > 0; j >>= 1)
                #pragma unroll
                for (int i = 0; i < 16; ++i) {
                    const int l = i | j;
                    if (l > i) {
                        const u64 a = list[i], bv = list[l];
                        const bool sw = (a < bv);
                        list[i] = sw ? bv : a;
                        list[l] = sw ? a : bv;
                    }
                }
        }
    }

    __syncthreads();   // all waves done with sf before aliasing as keys
    #pragma unroll
    for (int k = 0; k < KTOP; ++k) sh.keys[q][k][lane] = list[k];
    __syncthreads();

    // per-row 4-way merge of sorted lists -> sorted 16-list, write to ws
    if (tid < 64) {
        int h0 = 0, h1 = 0, h2 = 0, h3 = 0;
        const int row_g = b * NPTS + chunk * 64 + tid;
        u64* dst = part + ((size_t)row_g * SPLIT + s) * KTOP;
        for (int k = 0; k < KTOP; ++k) {
            u64 best = 0; int bq = 0;
            u64 v0 = (h0 < KTOP) ? sh.keys[0][h0][tid] : 0ull;
            u64 v1 = (h1 < KTOP) ? sh.keys[1][h1][tid] : 0ull;
            u64 v2 = (h2 < KTOP) ? sh.keys[2][h2][tid] : 0ull;
            u64 v3 = (h3 < KTOP) ? sh.keys[3][h3][tid] : 0ull;
            if (v0 > best) { best = v0; bq = 0; }
            if (v1 > best) { best = v1; bq = 1; }
            if (v2 > best) { best = v2; bq = 2; }
            if (v3 > best) { best = v3; bq = 3; }
            h0 += (bq == 0); h1 += (bq == 1); h2 += (bq == 2); h3 += (bq == 3);
            dst[k] = best;
        }
    }
}

// ---------------------------------------------------------------------------
// Kernel 2: merge SPLIT sorted 16-lists per row, gather sx_c, write tgt_out.
// Block = 16 rows, 256 threads. Grid = NROWS/16 = 1024 (4 blocks/CU for
// scattered-gather memory parallelism).
// ---------------------------------------------------------------------------
__global__ __launch_bounds__(256, 4) void merge_gather_kernel(
    const float* __restrict__ x_c,
    const u64*   __restrict__ part,
    const int*   __restrict__ flow_p,
    float*       __restrict__ out,
    int SPLIT)
{
    __shared__ u64 kk[16 * 4 * KTOP];   // up to 8 KiB
    __shared__ int sel[16][KTOP];

    const int tid  = threadIdx.x;
    const int rb   = blockIdx.x * 16;        // first global row of this block
    const int b    = rb / NPTS;
    const int nper = SPLIT * KTOP;

    for (int i = tid; i < 16 * nper; i += 256)
        kk[i] = part[(size_t)rb * nper + i];
    __syncthreads();

    if (tid < 16) {
        const u64* rk = &kk[tid * nper];
        int h0 = 0, h1 = 0, h2 = 0, h3 = 0;
        for (int k = 0; k < KTOP; ++k) {
            u64 best = 0; int bq = 0;
            u64 v0 = rk[h0];
            if (v0 > best) { best = v0; bq = 0; }
            if (SPLIT > 1) {
                u64 v1 = rk[KTOP + h1];
                if (v1 > best) { best = v1; bq = 1; }
            }
            if (SPLIT > 2) {
                u64 v2 = rk[2 * KTOP + h2];
                if (v2 > best) { best = v2; bq = 2; }
                u64 v3 = rk[3 * KTOP + h3];
                if (v3 > best) { best = v3; bq = 3; }
            }
            h0 += (bq == 0); h1 += (bq == 1); h2 += (bq == 2); h3 += (bq == 3);
            sel[tid][k] = 2047 - (int)(best & 0xFFFFFFFFull);
        }
    }
    __syncthreads();

    const int flow = flow_p[0];
    const float* xb = x_c + (size_t)b * CCH * NF * NPTS;
    const float* xf = xb + (size_t)flow * NPTS;   // xf[c*2*2048 + m]

    // sx_c[b, n, k, c] = x_c[b, c, flow, sel[n][k]]
    for (int e = tid; e < 16 * KTOP * CCH; e += 256) {
        const int L = e / (KTOP * CCH);
        const int r = e % (KTOP * CCH);
        const int k = r / CCH;
        const int c = r % CCH;
        out[((size_t)(rb + L) * KTOP + k) * CCH + c] =
            xf[(size_t)c * NF * NPTS + sel[L][k]];
    }

    // tgt_out[b, c, n] = x_c[b, c, flow, n] — 192 elems for this block's rows
    if (tid < CCH * 16) {
        const int c = tid >> 4;
        const int L = tid & 15;
        const int nn = (rb % NPTS) + L;
        out[TGT_BASE + ((size_t)b * CCH + c) * NPTS + nn] =
            xf[(size_t)c * NF * NPTS + nn];
    }
}

// ---------------------------------------------------------------------------
extern "C" void kernel_launch(void* const* d_in, const int* in_sizes, int n_in,
                              void* d_out, int out_size, void* d_ws, size_t ws_size,
                              hipStream_t stream)
{
    const float* x_c    = (const float*)d_in[0];
    const int*   flow_p = (const int*)d_in[1];
    float*       out    = (float*)d_out;
    u64*         part   = (u64*)d_ws;

    const size_t need4 = (size_t)NROWS * 4 * KTOP * sizeof(u64);   // 8 MiB
    const int SPLIT = (ws_size >= need4) ? 4 : ((ws_size >= need4 / 2) ? 2 : 1);

    topk_part_kernel<<<BS * 32 * SPLIT, 256, 0, stream>>>(x_c, part, SPLIT);
    merge_gather_kernel<<<NROWS / 16, 256, 0, stream>>>(x_c, part, flow_p, out, SPLIT);
}

// Round 6
// 164.445 us; speedup vs baseline: 3.8817x; 1.1543x over previous
//
#include <hip/hip_runtime.h>
#include <math.h>

#define BS   8
#define NPTS 2048
#define CCH  12      // channels per flow
#define NF   2       // flow dim
#define DIM  24      // NF*CCH, feats order: d = f*12 + c
#define KTOP 16

#define NROWS    (BS * NPTS)
#define TGT_BASE (NROWS * KTOP * CCH)   // 3145728

#define SPLIT 2      // candidate halves per row (ws 'part' = 4 MiB)
#define WPB   8      // waves per topk block (512 threads)
#define CPW   128    // candidates per wave (SPLIT*WPB*CPW = 2048)

typedef unsigned long long u64;
typedef unsigned int       u32;

// ws layout (bytes): [0) feats 16384*24*4 = 1572864 | raw 16384*12*4 = 786432 | part
#define WS_FEATS 0
#define WS_RAW   (NROWS * DIM * 4)
#define WS_PART  (WS_RAW + NROWS * CCH * 4)        // 8B aligned

// Emulate np.linalg.norm(v) + 1e-8 in float32 exactly (numpy pairwise sum, n=24):
//   r[j] = (s[j] + s[j+8]) + s[j+16];  res = ((r0+r1)+(r2+r3)) + ((r4+r5)+(r6+r7))
__device__ __forceinline__ float np_norm_den(const float* __restrict__ v)
{
#pragma clang fp contract(off)
    float s[DIM];
    #pragma unroll
    for (int d = 0; d < DIM; ++d) s[d] = v[d] * v[d];
    float r[8];
    #pragma unroll
    for (int j = 0; j < 8; ++j) r[j] = (s[j] + s[j + 8]) + s[j + 16];
    float res = ((r[0] + r[1]) + (r[2] + r[3])) + ((r[4] + r[5]) + (r[6] + r[7]));
    return sqrtf(res) + 1e-8f;
}

// Monotone float -> u32 (preserves total order for finite floats)
__device__ __forceinline__ u32 ordf(float f)
{
    u32 u = __float_as_uint(f);
    return ((int)u >= 0) ? (u | 0x80000000u) : ~u;
}

// ---------------------------------------------------------------------------
// Kernel 0: normalize every row (numpy-exact fp32), write contiguous feats,
// raw flow-slice (gather-friendly), and the tgt_out output.
// ---------------------------------------------------------------------------
__global__ __launch_bounds__(256) void prep_kernel(
    const float* __restrict__ x_c,     // [8][12][2][2048]
    const int*   __restrict__ flow_p,
    float*       __restrict__ feats,   // [NROWS][DIM] normalized
    float*       __restrict__ raw,     // [NROWS][CCH] raw flow slice
    float*       __restrict__ out)
{
    const int t = blockIdx.x * 256 + threadIdx.x;   // global row
    const int b = t >> 11;
    const int n = t & (NPTS - 1);
    const float* xb = x_c + (size_t)b * CCH * NF * NPTS;

    float v[DIM];
    {
#pragma clang fp contract(off)
        #pragma unroll
        for (int c = 0; c < CCH; ++c)
            #pragma unroll
            for (int f = 0; f < NF; ++f)
                v[f * CCH + c] = xb[(c * NF + f) * NPTS + n];

        const float den = np_norm_den(v);
        float* fo = feats + (size_t)t * DIM;
        #pragma unroll
        for (int d = 0; d < DIM; ++d) fo[d] = v[d] / den;
    }

    const int flow = flow_p[0];
    float* ro = raw + (size_t)t * CCH;
    #pragma unroll
    for (int c = 0; c < CCH; ++c) {
        const float xv = flow ? v[CCH + c] : v[c];   // raw value, pre-norm
        ro[c] = xv;
        out[TGT_BASE + ((size_t)b * CCH + c) * NPTS + n] = xv;   // tgt_out
    }
}

// ---------------------------------------------------------------------------
// Kernel 1: per-row partial top-16. Block = (b, 64-row chunk, split s).
// 512 thr = 8 waves; lane = row. Wave w streams candidates
// [s*1024 + w*128, +128): wave-uniform addresses (readfirstlane) so feature
// loads become s_load into SGPRs; dot = 24 x v_fma_f32(sgpr,vgpr,acc) —
// exact sequential fp32 chain. NO LDS / NO barriers in the hot loop.
// Batch-16 branchless bitonic maintains the sorted-desc u64-key top-16.
// ---------------------------------------------------------------------------
__global__ __launch_bounds__(512, 4) void topk_kernel(
    const float* __restrict__ feats,
    u64*         __restrict__ part)    // [NROWS][SPLIT][KTOP]
{
    __shared__ u64 keys[WPB][KTOP][64];   // 64 KiB, used only in the epilogue

    const int tid  = threadIdx.x;
    const int lane = tid & 63;
    const int w    = __builtin_amdgcn_readfirstlane(tid >> 6);  // uniform wave id
    int bi = blockIdx.x;
    const int s     = bi & (SPLIT - 1); bi >>= 1;
    const int chunk = bi & 31;
    const int b     = bi >> 5;
    const int row   = b * NPTS + chunk * 64 + lane;

    // own row's normalized vector (per-lane, vector loads)
    float rfn[DIM];
    {
        const float* fr = feats + (size_t)row * DIM;
        #pragma unroll
        for (int d = 0; d < DIM; ++d) rfn[d] = fr[d];
    }

    // sorted-descending top-16 packed keys; sentinel 0 < any real key
    u64 list[KTOP];
    #pragma unroll
    for (int k = 0; k < KTOP; ++k) list[k] = 0ull;

    const int    mg0 = s * (NPTS / SPLIT) + w * CPW;
    const float* cb  = feats + ((size_t)b * NPTS + mg0) * DIM;  // uniform base

    for (int jb = 0; jb < CPW; jb += 16) {
        u64 bkey[KTOP];
        #pragma unroll 4
        for (int jj = 0; jj < 16; ++jj) {
            const float* cp = cb + (size_t)(jb + jj) * DIM;   // uniform -> s_load
            float acc = 0.0f;
            #pragma unroll
            for (int d = 0; d < DIM; ++d)
                acc = __builtin_fmaf(cp[d], rfn[d], acc);     // exact chain
            const int mg = mg0 + jb + jj;
            bkey[jj] = ((u64)ordf(acc) << 32) | (u32)(2047 - mg);
        }
        // bitonic sort batch ASCENDING (branchless, fully unrolled)
        #pragma unroll
        for (int k = 2; k <= 16; k <<= 1)
            #pragma unroll
            for (int j = k >> 1; j > 0; j >>= 1)
                #pragma unroll
                for (int i = 0; i < 16; ++i) {
                    const int l = i | j;
                    if (l > i) {
                        const bool up = ((i & k) == 0);
                        const u64 a = bkey[i], bv = bkey[l];
                        const bool sw = up ? (a > bv) : (a < bv);
                        bkey[i] = sw ? bv : a;
                        bkey[l] = sw ? a : bv;
                    }
                }
        // merge: list desc + batch asc -> elementwise max is bitonic
        #pragma unroll
        for (int i = 0; i < 16; ++i) {
            const u64 a = list[i], bv = bkey[i];
            list[i] = (a > bv) ? a : bv;
        }
        // bitonic cleanup -> sorted descending
        #pragma unroll
        for (int j = 8; j > 0; j >>= 1)
            #pragma unroll
            for (int i = 0; i < 16; ++i) {
                const int l = i | j;
                if (l > i) {
                    const u64 a = list[i], bv = list[l];
                    const bool sw = (a < bv);
                    list[i] = sw ? bv : a;
                    list[l] = sw ? a : bv;
                }
            }
    }

    #pragma unroll
    for (int k = 0; k < KTOP; ++k) keys[w][k][lane] = list[k];
    __syncthreads();

    // per-row 8-way merge of sorted lists -> sorted 16-list, write to ws
    if (tid < 64) {
        int h0 = 0, h1 = 0, h2 = 0, h3 = 0, h4 = 0, h5 = 0, h6 = 0, h7 = 0;
        const int rg = b * NPTS + chunk * 64 + tid;
        u64* dst = part + ((size_t)rg * SPLIT + s) * KTOP;
        for (int k = 0; k < KTOP; ++k) {
            u64 best = 0; int bq = 0;
            u64 v0 = (h0 < KTOP) ? keys[0][h0][tid] : 0ull;
            u64 v1 = (h1 < KTOP) ? keys[1][h1][tid] : 0ull;
            u64 v2 = (h2 < KTOP) ? keys[2][h2][tid] : 0ull;
            u64 v3 = (h3 < KTOP) ? keys[3][h3][tid] : 0ull;
            u64 v4 = (h4 < KTOP) ? keys[4][h4][tid] : 0ull;
            u64 v5 = (h5 < KTOP) ? keys[5][h5][tid] : 0ull;
            u64 v6 = (h6 < KTOP) ? keys[6][h6][tid] : 0ull;
            u64 v7 = (h7 < KTOP) ? keys[7][h7][tid] : 0ull;
            if (v0 > best) { best = v0; bq = 0; }
            if (v1 > best) { best = v1; bq = 1; }
            if (v2 > best) { best = v2; bq = 2; }
            if (v3 > best) { best = v3; bq = 3; }
            if (v4 > best) { best = v4; bq = 4; }
            if (v5 > best) { best = v5; bq = 5; }
            if (v6 > best) { best = v6; bq = 6; }
            if (v7 > best) { best = v7; bq = 7; }
            h0 += (bq == 0); h1 += (bq == 1); h2 += (bq == 2); h3 += (bq == 3);
            h4 += (bq == 4); h5 += (bq == 5); h6 += (bq == 6); h7 += (bq == 7);
            dst[k] = best;
        }
    }
}

// ---------------------------------------------------------------------------
// Kernel 2: merge the SPLIT=2 sorted lists per row, gather sx_c from the
// contiguous raw flow-slice. Block = 16 rows, 256 threads, grid 1024.
// ---------------------------------------------------------------------------
__global__ __launch_bounds__(256) void gather_kernel(
    const float* __restrict__ raw,     // [NROWS][CCH]
    const u64*   __restrict__ part,
    float*       __restrict__ out)
{
    __shared__ u64 kk[16 * SPLIT * KTOP];   // 4 KiB
    __shared__ int sel[16][KTOP];

    const int tid = threadIdx.x;
    const int rb  = blockIdx.x * 16;        // first global row of this block
    const int b   = rb >> 11;               // same batch for all 16 rows

    for (int i = tid; i < 16 * SPLIT * KTOP; i += 256)
        kk[i] = part[(size_t)rb * SPLIT * KTOP + i];
    __syncthreads();

    if (tid < 16) {
        const u64* rk = &kk[tid * SPLIT * KTOP];
        int h0 = 0, h1 = 0;
        for (int k = 0; k < KTOP; ++k) {
            const u64 v0 = rk[h0];
            const u64 v1 = rk[KTOP + h1];
            const bool t1 = (v1 > v0);
            const u64 best = t1 ? v1 : v0;
            h0 += !t1; h1 += t1;
            sel[tid][k] = 2047 - (int)(best & 0xFFFFFFFFull);
        }
    }
    __syncthreads();

    // sx_c[b, n, k, c] = raw[(b*2048 + sel)*12 + c]  (contiguous 12 floats)
    for (int e = tid; e < 16 * KTOP * CCH; e += 256) {
        const int L = e / (KTOP * CCH);
        const int r = e % (KTOP * CCH);
        const int k = r / CCH;
        const int c = r % CCH;
        out[((size_t)(rb + L) * KTOP + k) * CCH + c] =
            raw[((size_t)b * NPTS + sel[L][k]) * CCH + c];
    }
}

// ---------------------------------------------------------------------------
extern "C" void kernel_launch(void* const* d_in, const int* in_sizes, int n_in,
                              void* d_out, int out_size, void* d_ws, size_t ws_size,
                              hipStream_t stream)
{
    const float* x_c    = (const float*)d_in[0];
    const int*   flow_p = (const int*)d_in[1];
    float*       out    = (float*)d_out;

    float* feats = (float*)((char*)d_ws + WS_FEATS);
    float* raw   = (float*)((char*)d_ws + WS_RAW);
    u64*   part  = (u64*)  ((char*)d_ws + WS_PART);

    prep_kernel<<<NROWS / 256, 256, 0, stream>>>(x_c, flow_p, feats, raw, out);
    topk_kernel<<<BS * 32 * SPLIT, 512, 0, stream>>>(feats, part);
    gather_kernel<<<NROWS / 16, 256, 0, stream>>>(raw, part, out);
}